// Round 6
// baseline (1977.230 us; speedup 1.0000x reference)
//
#include <hip/hip_runtime.h>
#include <math.h>

#define DC_C 6
#define NRANGE 8          // slot ranges, aligned to blockIdx%8 -> XCD round-robin
#define VCH 2048          // vars per block-chunk in build_b

typedef unsigned uint4v __attribute__((ext_vector_type(4)));

// Per-check compressed message record (12 B).
// x = bits(Asp) = sprod*(relu(min2-b)-a)  [value on argmin edges]
// y = bits(Bsp) = sprod*(relu(min1-b)-a)  [value on other edges]
// z = masks: bits 0-5 amin, 8-13 negative-sign, 16-21 zero-sign
// c2v_j = sg_j * (amin_j ? Asp : Bsp), sg_j in {+1,-1,0}.

__device__ __forceinline__ float c2v_bits(unsigned x, unsigned y, unsigned z, int j) {
    float val = ((z >> j) & 1u) ? __uint_as_float(x) : __uint_as_float(y);
    float s = ((z >> (16 + j)) & 1u) ? 0.0f
            : (((z >> (8 + j)) & 1u) ? -1.0f : 1.0f);
    return s * val;
}
__device__ __forceinline__ float c2v_from_rec(uint3 r, int j) {
    return c2v_bits(r.x, r.y, r.z, j);
}
__device__ __forceinline__ float c2v4(uint4v r, int j) {
    return c2v_bits(r.x, r.y, r.z, j);
}

__device__ __forceinline__ uint3 make_rec(const float pv[DC_C], float b, float a) {
    float sprod = 1.0f;
    float m1 = INFINITY, m2 = INFINITY;
    float mg[DC_C];
    unsigned int ng = 0, zr = 0;
#pragma unroll
    for (int j = 0; j < DC_C; ++j) {
        float x = pv[j];
        float m = fabsf(x);
        mg[j] = m;
        if (x < 0.0f) { ng |= (1u << j); sprod = -sprod; }
        else if (x == 0.0f) { zr |= (1u << j); sprod = 0.0f; }
        if (m < m1) { m2 = m1; m1 = m; }
        else if (m < m2) { m2 = m; }
    }
    unsigned int am = 0;
#pragma unroll
    for (int j = 0; j < DC_C; ++j) am |= (mg[j] == m1) ? (1u << j) : 0u;
    // ties: multiple amin bits imply m2==m1 -> A==B, identical to the
    // reference's first-argmin rule.
    float A = fmaxf(m2 - b, 0.0f) - a;
    float B = fmaxf(m1 - b, 0.0f) - a;
    return make_uint3(__float_as_uint(sprod * A),
                      __float_as_uint(sprod * B),
                      am | (ng << 8) | (zr << 16));
}

// Phase A: slot assignment (nibble-packed counters). Pinned at the
// device-atomic floor (~61 us) — accepted structural cost.
__global__ void build_a(const int* __restrict__ edge_chk,
                        unsigned int* __restrict__ cnt8,
                        unsigned long long* __restrict__ pos64,
                        int n) {
    int v = blockIdx.x * blockDim.x + threadIdx.x;
    if (v >= n) return;
    int c0 = edge_chk[v * 3 + 0];
    int c1 = edge_chk[v * 3 + 1];
    int c2 = edge_chk[v * 3 + 2];
    unsigned int sh0 = (c0 & 7) * 4, sh1 = (c1 & 7) * 4, sh2 = (c2 & 7) * 4;
    unsigned int o0 = atomicAdd(&cnt8[c0 >> 3], 1u << sh0);
    unsigned int o1 = atomicAdd(&cnt8[c1 >> 3], 1u << sh1);
    unsigned int o2 = atomicAdd(&cnt8[c2 >> 3], 1u << sh2);
    int j0 = (o0 >> sh0) & 0xF;
    int j1 = (o1 >> sh1) & 0xF;
    int j2 = (o2 >> sh2) & 0xF;
    unsigned long long s0 = (unsigned long long)(c0 * DC_C + j0);
    unsigned long long s1 = (unsigned long long)(c1 * DC_C + j1);
    unsigned long long s2 = (unsigned long long)(c2 * DC_C + j2);
    pos64[v] = s0 | (s1 << 21) | (s2 << 42);
}

// Phase B: invert pos64 -> vmap (slot -> variable). Range-partitioned so each
// vmap line is filled from one XCD (blockIdx%8 heuristic; perf-only).
__global__ void build_b(const unsigned long long* __restrict__ pos64,
                        int* __restrict__ vmap,
                        int n, int E) {
    int r = blockIdx.x & (NRANGE - 1);
    int chunk = blockIdx.x >> 3;
    int lo = r * (E / NRANGE);
    int hi = lo + (E / NRANGE);
    int base = chunk * VCH;
#pragma unroll
    for (int rr = 0; rr < VCH / 256; ++rr) {
        int v = base + rr * 256 + threadIdx.x;
        if (v >= n) break;
        unsigned long long pk = pos64[v];
        int s0 = (int)(pk & 0x1FFFFF);
        int s1 = (int)((pk >> 21) & 0x1FFFFF);
        int s2 = (int)((pk >> 42) & 0x1FFFFF);
        if (s0 >= lo && s0 < hi) vmap[s0] = v;
        if (s1 >= lo && s1 < hi) vmap[s1] = v;
        if (s2 >= lo && s2 < hi) vmap[s2] = v;
    }
}

// Agent-coherent write-through store (R3-proven visible cross-XCD).
__device__ __forceinline__ void store_wt(unsigned int* a, unsigned int v) {
    __hip_atomic_store(a, v, __ATOMIC_RELAXED, __HIP_MEMORY_SCOPE_AGENT);
}
__device__ __forceinline__ void store_wt_f(float* a, float v) {
    __hip_atomic_store(a, v, __ATOMIC_RELAXED, __HIP_MEMORY_SCOPE_AGENT);
}

// Dispatch-boundary-equivalent grid barrier:
//  arrival: vmcnt(0) (WT stores at LLC; __syncthreads already drained the
//           block's waves) + RELAXED fetch_add; spin RELAXED agent loads
//           (LLC-direct, no cache side effects — R3-proven to make progress).
//  release: ONE agent-acquire fence (= one buffer_inv) PER XCD, by a
//           CAS-elected leader on the physical XCD (s_getreg XCC_ID, m09),
//           then a flag store; followers spin the flag, NO inv (their L1
//           staleness is handled by sc0 gathers in the compute phases).
//  R2 failed on per-poll inv; R3 on 128 staggered per-block invs/XCD wiping
//  each other's refills. This is 1 inv/XCD/phase — same as a dispatch.
// Watchdogs bound both spins so violated assumptions fail absmax with live
// counters instead of hanging the container.
__device__ __forceinline__ void grid_sync(unsigned int* bar,
                                          unsigned int* xclaim,
                                          unsigned int* xgo,
                                          unsigned int target,
                                          unsigned int prev) {
    __syncthreads();
    if (threadIdx.x == 0) {
        asm volatile("s_waitcnt vmcnt(0)" ::: "memory");
        __hip_atomic_fetch_add(bar, 1u, __ATOMIC_RELAXED, __HIP_MEMORY_SCOPE_AGENT);
        unsigned int spins = 0;
        while (__hip_atomic_load(bar, __ATOMIC_RELAXED, __HIP_MEMORY_SCOPE_AGENT) < target) {
            __builtin_amdgcn_s_sleep(8);
            if (++spins > (1u << 21)) break;   // ~0.5s watchdog
        }
        unsigned int xcd = __builtin_amdgcn_s_getreg((3u << 11) | 20u) & 7u; // HW_REG_XCC_ID
        unsigned int* go = xgo + xcd * 16;
        if (__hip_atomic_load(go, __ATOMIC_RELAXED, __HIP_MEMORY_SCOPE_AGENT) != target) {
            unsigned int exp = prev;
            if (__hip_atomic_compare_exchange_strong(
                    xclaim + xcd * 16, &exp, target,
                    __ATOMIC_RELAXED, __ATOMIC_RELAXED, __HIP_MEMORY_SCOPE_AGENT)) {
                __builtin_amdgcn_fence(__ATOMIC_ACQUIRE, "agent");   // one L2 inv
                __hip_atomic_store(go, target, __ATOMIC_RELAXED, __HIP_MEMORY_SCOPE_AGENT);
            } else {
                unsigned int s2 = 0;
                while (__hip_atomic_load(go, __ATOMIC_RELAXED, __HIP_MEMORY_SCOPE_AGENT) != target) {
                    __builtin_amdgcn_s_sleep(2);
                    if (++s2 > (1u << 23)) break;
                }
            }
        }
    }
    __syncthreads();
}

// Persistent fused loop: 1024 blocks x 256 threads. VGPR cap 128
// (__launch_bounds__) => residency capacity >= 8 blocks/CU; grid uses 4/CU —
// 2x co-residency margin (R3 evidence). Each thread owns 1 check AND 2 vars
// (n_chk == n/2). Statics (vmap, pos64 slots, llr) pinned in registers for
// all 19 phases; check's rec carried in registers (no old-rec re-read).
// All mutable-data gathers are inline-asm sc0 loads (bypass L1, hit the
// leader-inv'd L2), batched 6-wide with one vmcnt(0) inside the asm so
// memory-level parallelism is preserved.
__global__ void __launch_bounds__(256, 4)
fused_loop(const float* __restrict__ llr,
           const int* __restrict__ vmap,
           const unsigned long long* __restrict__ pos64,
           unsigned int* __restrict__ recs_u,
           float* __restrict__ p,
           const float* __restrict__ beta,
           const float* __restrict__ alpha,
           float* __restrict__ out,
           unsigned int* __restrict__ bar,
           unsigned int* __restrict__ xclaim,
           unsigned int* __restrict__ xgo,
           int n, int T, unsigned int nb) {
    const int tid = blockIdx.x * blockDim.x + threadIdx.x;  // check id == var-pair id

    // ---- check-role statics (registers for the whole kernel) ----
    const int cb = tid * DC_C;
    int2 w01 = *(const int2*)(vmap + cb);
    int2 w23 = *(const int2*)(vmap + cb + 2);
    int2 w45 = *(const int2*)(vmap + cb + 4);

    // ---- var-role statics ----
    ulonglong2 pk2 = *(const ulonglong2*)(pos64 + (size_t)tid * 2);
    float2 ll = *(const float2*)(llr + (size_t)tid * 2);
    int sA0 = (int)(pk2.x & 0x1FFFFF);
    int sA1 = (int)((pk2.x >> 21) & 0x1FFFFF);
    int sA2 = (int)((pk2.x >> 42) & 0x1FFFFF);
    int sB0 = (int)(pk2.y & 0x1FFFFF);
    int sB1 = (int)((pk2.y >> 21) & 0x1FFFFF);
    int sB2 = (int)((pk2.y >> 42) & 0x1FFFFF);
    int rjA0 = sA0 % DC_C, rjA1 = sA1 % DC_C, rjA2 = sA2 % DC_C;
    int rjB0 = sB0 % DC_C, rjB1 = sB1 % DC_C, rjB2 = sB2 % DC_C;
    // byte offsets of the 6 gathered recs (12 B stride)
    const char* rbase = (const char*)recs_u;
    const char* gA0 = rbase + (size_t)(sA0 / DC_C) * 12;
    const char* gA1 = rbase + (size_t)(sA1 / DC_C) * 12;
    const char* gA2 = rbase + (size_t)(sA2 / DC_C) * 12;
    const char* gB0 = rbase + (size_t)(sB0 / DC_C) * 12;
    const char* gB1 = rbase + (size_t)(sB1 / DC_C) * 12;
    const char* gB2 = rbase + (size_t)(sB2 / DC_C) * 12;

    unsigned int rx = 0, ry = 0, rz = 0;   // reg-carried rec
    unsigned int phase = 0;

#pragma unroll 1
    for (int t = 0; t < T; ++t) {
        // ---------- CHECK phase ----------
        const float* src = (t == 0) ? llr : p;   // p_init == llr, c2v_0 == 0
        float g0, g1, g2, g3, g4, g5;
        {
            const float* a0 = src + w01.x;
            const float* a1 = src + w01.y;
            const float* a2 = src + w23.x;
            const float* a3 = src + w23.y;
            const float* a4 = src + w45.x;
            const float* a5 = src + w45.y;
            asm volatile(
                "global_load_dword %0, %6, off sc0\n\t"
                "global_load_dword %1, %7, off sc0\n\t"
                "global_load_dword %2, %8, off sc0\n\t"
                "global_load_dword %3, %9, off sc0\n\t"
                "global_load_dword %4, %10, off sc0\n\t"
                "global_load_dword %5, %11, off sc0\n\t"
                "s_waitcnt vmcnt(0)"
                : "=&v"(g0), "=&v"(g1), "=&v"(g2), "=&v"(g3), "=&v"(g4), "=&v"(g5)
                : "v"(a0), "v"(a1), "v"(a2), "v"(a3), "v"(a4), "v"(a5)
                : "memory");
        }
        float b = beta[t];
        float a = alpha[t];
        float pv[DC_C];
        {
            float gg[DC_C] = {g0, g1, g2, g3, g4, g5};
#pragma unroll
            for (int j = 0; j < DC_C; ++j) {
                float old_ = (t == 0) ? 0.0f : c2v_bits(rx, ry, rz, j);
                pv[j] = gg[j] - old_;
            }
        }
        uint3 nr = make_rec(pv, b, a);
        rx = nr.x; ry = nr.y; rz = nr.z;
        {
            unsigned int* rp = recs_u + (size_t)tid * 3;
            store_wt(rp + 0, rx);
            store_wt(rp + 1, ry);
            store_wt(rp + 2, rz);
        }

        ++phase;
        grid_sync(bar, xclaim, xgo, phase * nb, (phase - 1) * nb);

        // ---------- VAR / FINAL phase ----------
        uint4v q0, q1, q2, q3, q4, q5;   // dwordx4: 12B rec + 4B overread (in-ws)
        asm volatile(
            "global_load_dwordx4 %0, %6, off sc0\n\t"
            "global_load_dwordx4 %1, %7, off sc0\n\t"
            "global_load_dwordx4 %2, %8, off sc0\n\t"
            "global_load_dwordx4 %3, %9, off sc0\n\t"
            "global_load_dwordx4 %4, %10, off sc0\n\t"
            "global_load_dwordx4 %5, %11, off sc0\n\t"
            "s_waitcnt vmcnt(0)"
            : "=&v"(q0), "=&v"(q1), "=&v"(q2), "=&v"(q3), "=&v"(q4), "=&v"(q5)
            : "v"(gA0), "v"(gA1), "v"(gA2), "v"(gB0), "v"(gB1), "v"(gB2)
            : "memory");
        float ca0 = c2v4(q0, rjA0);
        float ca1 = c2v4(q1, rjA1);
        float ca2 = c2v4(q2, rjA2);
        float cb0 = c2v4(q3, rjB0);
        float cb1 = c2v4(q4, rjB1);
        float cb2 = c2v4(q5, rjB2);
        float pa = ll.x + ((ca0 + ca1) + ca2);
        float pb = ll.y + ((cb0 + cb1) + cb2);
        if (t + 1 < T) {
            store_wt_f(p + (size_t)tid * 2,     pa);
            store_wt_f(p + (size_t)tid * 2 + 1, pb);
            ++phase;
            grid_sync(bar, xclaim, xgo, phase * nb, (phase - 1) * nb);
        } else {
            float2 bits, post;
            bits.x = (pa < 0.0f) ? 1.0f : 0.0f;
            bits.y = (pb < 0.0f) ? 1.0f : 0.0f;
            post.x = pa; post.y = pb;
            *(float2*)(out + (size_t)tid * 2) = bits;
            *(float2*)(out + n + (size_t)tid * 2) = post;
        }
    }
}

// ---------- fallback path (verified R0 split pipeline) ----------
__global__ void check_kernel(const float* __restrict__ p,
                             const int* __restrict__ vmap,
                             uint3* __restrict__ recs,
                             const float* __restrict__ beta,
                             const float* __restrict__ alpha,
                             int t, int n_chk, int first) {
    int c = blockIdx.x * blockDim.x + threadIdx.x;
    if (c >= n_chk) return;
    int base = c * DC_C;
    int2 w01 = *(const int2*)(vmap + base);
    int2 w23 = *(const int2*)(vmap + base + 2);
    int2 w45 = *(const int2*)(vmap + base + 4);
    int w[DC_C] = {w01.x, w01.y, w23.x, w23.y, w45.x, w45.y};
    float pvv[DC_C];
#pragma unroll
    for (int j = 0; j < DC_C; ++j) pvv[j] = p[w[j]];
    float old_[DC_C];
    if (first) {
#pragma unroll
        for (int j = 0; j < DC_C; ++j) old_[j] = 0.0f;
    } else {
        uint3 rec = recs[c];
#pragma unroll
        for (int j = 0; j < DC_C; ++j) old_[j] = c2v_from_rec(rec, j);
    }
    float pv[DC_C];
#pragma unroll
    for (int j = 0; j < DC_C; ++j) pv[j] = pvv[j] - old_[j];
    recs[c] = make_rec(pv, beta[t], alpha[t]);
}

__global__ void var_kernel(const uint3* __restrict__ recs,
                           const unsigned long long* __restrict__ pos64,
                           const float* __restrict__ llr,
                           float* __restrict__ p,
                           int n2) {
    int i = blockIdx.x * blockDim.x + threadIdx.x;
    if (i >= n2) return;
    ulonglong2 pk2 = *(const ulonglong2*)(pos64 + (size_t)i * 2);
    float2 ll = *(const float2*)(llr + (size_t)i * 2);
    int a0 = (int)(pk2.x & 0x1FFFFF);
    int a1 = (int)((pk2.x >> 21) & 0x1FFFFF);
    int a2 = (int)((pk2.x >> 42) & 0x1FFFFF);
    int b0 = (int)(pk2.y & 0x1FFFFF);
    int b1 = (int)((pk2.y >> 21) & 0x1FFFFF);
    int b2 = (int)((pk2.y >> 42) & 0x1FFFFF);
    uint3 ra0 = recs[a0 / DC_C];
    uint3 ra1 = recs[a1 / DC_C];
    uint3 ra2 = recs[a2 / DC_C];
    uint3 rb0 = recs[b0 / DC_C];
    uint3 rb1 = recs[b1 / DC_C];
    uint3 rb2 = recs[b2 / DC_C];
    float2 o;
    o.x = ll.x + ((c2v_from_rec(ra0, a0 % DC_C)
                 + c2v_from_rec(ra1, a1 % DC_C))
                 + c2v_from_rec(ra2, a2 % DC_C));
    o.y = ll.y + ((c2v_from_rec(rb0, b0 % DC_C)
                 + c2v_from_rec(rb1, b1 % DC_C))
                 + c2v_from_rec(rb2, b2 % DC_C));
    *(float2*)(p + (size_t)i * 2) = o;
}

__global__ void final_kernel(const uint3* __restrict__ recs,
                             const unsigned long long* __restrict__ pos64,
                             const float* __restrict__ llr,
                             float* __restrict__ out,
                             int n2, int n) {
    int i = blockIdx.x * blockDim.x + threadIdx.x;
    if (i >= n2) return;
    ulonglong2 pk2 = *(const ulonglong2*)(pos64 + (size_t)i * 2);
    float2 ll = *(const float2*)(llr + (size_t)i * 2);
    int a0 = (int)(pk2.x & 0x1FFFFF);
    int a1 = (int)((pk2.x >> 21) & 0x1FFFFF);
    int a2 = (int)((pk2.x >> 42) & 0x1FFFFF);
    int b0 = (int)(pk2.y & 0x1FFFFF);
    int b1 = (int)((pk2.y >> 21) & 0x1FFFFF);
    int b2 = (int)((pk2.y >> 42) & 0x1FFFFF);
    uint3 ra0 = recs[a0 / DC_C];
    uint3 ra1 = recs[a1 / DC_C];
    uint3 ra2 = recs[a2 / DC_C];
    uint3 rb0 = recs[b0 / DC_C];
    uint3 rb1 = recs[b1 / DC_C];
    uint3 rb2 = recs[b2 / DC_C];
    float pa = ll.x + ((c2v_from_rec(ra0, a0 % DC_C)
                      + c2v_from_rec(ra1, a1 % DC_C))
                      + c2v_from_rec(ra2, a2 % DC_C));
    float pb = ll.y + ((c2v_from_rec(rb0, b0 % DC_C)
                      + c2v_from_rec(rb1, b1 % DC_C))
                      + c2v_from_rec(rb2, b2 % DC_C));
    float2 bits, post;
    bits.x = (pa < 0.0f) ? 1.0f : 0.0f;
    bits.y = (pb < 0.0f) ? 1.0f : 0.0f;
    post.x = pa;
    post.y = pb;
    *(float2*)(out + (size_t)i * 2) = bits;
    *(float2*)(out + n + (size_t)i * 2) = post;
}

extern "C" void kernel_launch(void* const* d_in, const int* in_sizes, int n_in,
                              void* d_out, int out_size, void* d_ws, size_t ws_size,
                              hipStream_t stream) {
    const float* llr      = (const float*)d_in[0];
    const float* beta     = (const float*)d_in[1];
    const float* alpha    = (const float*)d_in[2];
    const int*   edge_chk = (const int*)d_in[4];

    const int n  = in_sizes[0];       // 524288
    const int T  = in_sizes[1];       // 10
    const int E  = in_sizes[3];       // 1572864
    const int n_chk = E / DC_C;       // 262144 == n/2

    // Workspace (rebuilt every call; ws re-poisoned between calls)
    char* ws = (char*)d_ws;
    unsigned int*       cnt8   = (unsigned int*)ws;                      // 128 KB @ 0
    unsigned int*       bar    = (unsigned int*)(ws + (1u << 19));       // @512K
    unsigned int*       xclaim = (unsigned int*)(ws + (1u << 19) + 256);
    unsigned int*       xgo    = (unsigned int*)(ws + (1u << 19) + 1280);
    unsigned long long* pos64  = (unsigned long long*)(ws + (1u << 20)); // 4 MB @ 1
    int*                vmap   = (int*)(ws + (5u << 20));                // 6 MB @ 5
    unsigned int*       recs   = (unsigned int*)(ws + (11u << 20));      // 3 MB @ 11
    float*              p      = (float*)(ws + (14u << 20));             // 2 MB @ 14

    // zero cnt8 + whole barrier block in one memset
    hipMemsetAsync(ws, 0, (size_t)(1u << 19) + 4096, stream);
    build_a<<<(n + 255) / 256, 256, 0, stream>>>(edge_chk, cnt8, pos64, n);
    {
        int chunks = (n + VCH - 1) / VCH;
        build_b<<<chunks * NRANGE, 256, 0, stream>>>(pos64, vmap, n, E);
    }

    if (ws_size >= ((size_t)16 << 20) && n == 2 * n_chk && (n_chk & 255) == 0) {
        const int nblocks = n_chk / 256;  // 1024: 4/CU used, >=8/CU capacity
        fused_loop<<<nblocks, 256, 0, stream>>>(
            llr, vmap, pos64, recs, p, beta, alpha, (float*)d_out,
            bar, xclaim, xgo, n, T, (unsigned int)nblocks);
    } else {
        for (int t = 0; t < T; ++t) {
            const float* src = (t == 0) ? llr : p;
            check_kernel<<<(n_chk + 255) / 256, 256, 0, stream>>>(
                src, vmap, (uint3*)recs, beta, alpha, t, n_chk, (t == 0) ? 1 : 0);
            if (t + 1 < T) {
                var_kernel<<<(n / 2 + 255) / 256, 256, 0, stream>>>(
                    (const uint3*)recs, pos64, llr, p, n / 2);
            } else {
                final_kernel<<<(n / 2 + 255) / 256, 256, 0, stream>>>(
                    (const uint3*)recs, pos64, llr, (float*)d_out, n / 2, n);
            }
        }
    }
}

// Round 7
// 365.796 us; speedup vs baseline: 5.4053x; 5.4053x over previous
//
#include <hip/hip_runtime.h>
#include <math.h>

#define DC_C 6
#define NRANGE 8          // slot ranges, aligned to blockIdx%8 -> XCD round-robin
#define VCH 2048          // vars per block-chunk in build_b

// Per-check compressed message record (12 B = uint3, one dwordx3 gather).
// x = bits(Asp) = sprod*(relu(min2-b)-a)  [value on argmin edges]
// y = bits(Bsp) = sprod*(relu(min1-b)-a)  [value on other edges]
// z = masks: bits 0-5 amin, 8-13 negative-sign, 16-21 zero-sign
// c2v_j = sg_j * (amin_j ? Asp : Bsp), sg_j in {+1,-1,0}.
//
// SESSION LEDGER (why this split structure is final):
//  - persistent fusion w/ software grid barrier: 3 implementations (R2 per-poll
//    inv, R3 per-block inv, R6 XCD-leader inv + sc0 gathers) all converge at
//    ~95-100 us/phase vs 14 us/dispatch — agent-scope coherence costs ~7x the
//    CP dispatch path, which keeps per-XCD L2s warm across dispatches.
//  - v2c-slot formulation (R4, 482 us): random 4B scatters create partial-line
//    dirty merges across 8 non-coherent L2s. Random READS cheap, WRITES poison.
//  - two-hop fused check (R5, 438 us): 18 gather-reqs/check vs 12 — request
//    count, not dispatch count, is the iteration-phase limiter.

__device__ __forceinline__ float c2v_from_rec(uint3 r, int j) {
    float val = ((r.z >> j) & 1u) ? __uint_as_float(r.x) : __uint_as_float(r.y);
    float s = ((r.z >> (16 + j)) & 1u) ? 0.0f
            : (((r.z >> (8 + j)) & 1u) ? -1.0f : 1.0f);
    return s * val;
}

// Phase A: slot assignment (nibble-packed counters: 8 checks/word, 4b each;
// count <= 6 so nibbles never carry). Pinned at the device-atomic floor:
// 1.57M atomics x ~34 B HBM write-through each = 53 MB at ~940 GB/s = ~61 us.
// Invariant under occupancy, pipelining, and counter-footprint changes
// (R3/R4/R7 evidence) — accepted structural cost.
__global__ void build_a(const int* __restrict__ edge_chk,
                        unsigned int* __restrict__ cnt8,
                        unsigned long long* __restrict__ pos64,
                        int n) {
    int v = blockIdx.x * blockDim.x + threadIdx.x;
    if (v >= n) return;
    int c0 = edge_chk[v * 3 + 0];
    int c1 = edge_chk[v * 3 + 1];
    int c2 = edge_chk[v * 3 + 2];
    unsigned int sh0 = (c0 & 7) * 4, sh1 = (c1 & 7) * 4, sh2 = (c2 & 7) * 4;
    unsigned int o0 = atomicAdd(&cnt8[c0 >> 3], 1u << sh0);
    unsigned int o1 = atomicAdd(&cnt8[c1 >> 3], 1u << sh1);
    unsigned int o2 = atomicAdd(&cnt8[c2 >> 3], 1u << sh2);
    int j0 = (o0 >> sh0) & 0xF;
    int j1 = (o1 >> sh1) & 0xF;
    int j2 = (o2 >> sh2) & 0xF;
    unsigned long long s0 = (unsigned long long)(c0 * DC_C + j0);
    unsigned long long s1 = (unsigned long long)(c1 * DC_C + j1);
    unsigned long long s2 = (unsigned long long)(c2 * DC_C + j2);
    pos64[v] = s0 | (s1 << 21) | (s2 << 42);
}

// Phase B: invert pos64 -> vmap (slot -> variable). Only random write in the
// pipeline; range-partitioned so each vmap line is filled from one XCD
// (blockIdx%8 heuristic; perf-only, correctness-independent).
__global__ void build_b(const unsigned long long* __restrict__ pos64,
                        int* __restrict__ vmap,
                        int n, int E) {
    int r = blockIdx.x & (NRANGE - 1);
    int chunk = blockIdx.x >> 3;
    int lo = r * (E / NRANGE);
    int hi = lo + (E / NRANGE);
    int base = chunk * VCH;
#pragma unroll
    for (int rr = 0; rr < VCH / 256; ++rr) {
        int v = base + rr * 256 + threadIdx.x;
        if (v >= n) break;
        unsigned long long pk = pos64[v];
        int s0 = (int)(pk & 0x1FFFFF);
        int s1 = (int)((pk >> 21) & 0x1FFFFF);
        int s2 = (int)((pk >> 42) & 0x1FFFFF);
        if (s0 >= lo && s0 < hi) vmap[s0] = v;
        if (s1 >= lo && s1 < hi) vmap[s1] = v;
        if (s2 >= lo && s2 < hi) vmap[s2] = v;
    }
}

// Check-node update, 1 check/thread (measured optimum: R10's 2/thread halves
// block count to 2/CU and regresses; R3's extra waves are neutral).
// Coalesced: vmap (3x int2), old record, new record. Random: 6 p-gathers
// from a 2 MB per-XCD-L2-resident array. Plain loads/stores only (R9: NT
// hints on producer->consumer buffers defeat cross-dispatch L2 reuse).
__global__ void check_kernel(const float* __restrict__ p,     // llr at t=0
                             const int* __restrict__ vmap,
                             uint3* __restrict__ recs,
                             const float* __restrict__ beta,
                             const float* __restrict__ alpha,
                             int t, int n_chk, int first) {
    int c = blockIdx.x * blockDim.x + threadIdx.x;
    if (c >= n_chk) return;
    int base = c * DC_C;
    int2 w01 = *(const int2*)(vmap + base);
    int2 w23 = *(const int2*)(vmap + base + 2);
    int2 w45 = *(const int2*)(vmap + base + 4);
    int w[DC_C] = {w01.x, w01.y, w23.x, w23.y, w45.x, w45.y};
    float pv[DC_C];
#pragma unroll
    for (int j = 0; j < DC_C; ++j) pv[j] = p[w[j]];

    float old_[DC_C];
    if (first) {
#pragma unroll
        for (int j = 0; j < DC_C; ++j) old_[j] = 0.0f;
    } else {
        uint3 rec = recs[c];
#pragma unroll
        for (int j = 0; j < DC_C; ++j) old_[j] = c2v_from_rec(rec, j);
    }

    float b = beta[t];
    float a = alpha[t];
    float sprod = 1.0f;
    float m1 = INFINITY, m2 = INFINITY;
    float mg[DC_C];
    unsigned int ng = 0, zr = 0;
#pragma unroll
    for (int j = 0; j < DC_C; ++j) {
        float x = pv[j] - old_[j];
        float m = fabsf(x);
        mg[j] = m;
        if (x < 0.0f) { ng |= (1u << j); sprod = -sprod; }
        else if (x == 0.0f) { zr |= (1u << j); sprod = 0.0f; }
        if (m < m1) { m2 = m1; m1 = m; }
        else if (m < m2) { m2 = m; }
    }
    unsigned int am = 0;
#pragma unroll
    for (int j = 0; j < DC_C; ++j) am |= (mg[j] == m1) ? (1u << j) : 0u;
    // ties: multiple amin bits imply m2==m1 -> A==B, identical to the
    // reference's first-argmin rule.
    float A = fmaxf(m2 - b, 0.0f) - a;
    float B = fmaxf(m1 - b, 0.0f) - a;
    recs[c] = make_uint3(__float_as_uint(sprod * A),
                         __float_as_uint(sprod * B),
                         am | (ng << 8) | (zr << 16));
}

// Variable-node update, 2 vars/thread (measured optimum).
// Coalesced: pos64 (ulonglong2), llr (float2), p write (float2).
// Random: 6 record gathers from 3 MB L2-resident recs.
__global__ void var_kernel(const uint3* __restrict__ recs,
                           const unsigned long long* __restrict__ pos64,
                           const float* __restrict__ llr,
                           float* __restrict__ p,
                           int n2) {       // n/2
    int i = blockIdx.x * blockDim.x + threadIdx.x;
    if (i >= n2) return;
    ulonglong2 pk2 = *(const ulonglong2*)(pos64 + i * 2);
    float2 ll = *(const float2*)(llr + i * 2);
    int a0 = (int)(pk2.x & 0x1FFFFF);
    int a1 = (int)((pk2.x >> 21) & 0x1FFFFF);
    int a2 = (int)((pk2.x >> 42) & 0x1FFFFF);
    int b0 = (int)(pk2.y & 0x1FFFFF);
    int b1 = (int)((pk2.y >> 21) & 0x1FFFFF);
    int b2 = (int)((pk2.y >> 42) & 0x1FFFFF);
    uint3 ra0 = recs[a0 / DC_C];
    uint3 ra1 = recs[a1 / DC_C];
    uint3 ra2 = recs[a2 / DC_C];
    uint3 rb0 = recs[b0 / DC_C];
    uint3 rb1 = recs[b1 / DC_C];
    uint3 rb2 = recs[b2 / DC_C];
    float ca0 = c2v_from_rec(ra0, a0 % DC_C);
    float ca1 = c2v_from_rec(ra1, a1 % DC_C);
    float ca2 = c2v_from_rec(ra2, a2 % DC_C);
    float cb0 = c2v_from_rec(rb0, b0 % DC_C);
    float cb1 = c2v_from_rec(rb1, b1 % DC_C);
    float cb2 = c2v_from_rec(rb2, b2 % DC_C);
    float2 o;
    o.x = ll.x + ((ca0 + ca1) + ca2);
    o.y = ll.y + ((cb0 + cb1) + cb2);
    *(float2*)(p + i * 2) = o;
}

// Final: posterior + hard decision, 2 vars/thread.
// out[0..n)=bits(f32 0/1), out[n..2n)=posterior.
__global__ void final_kernel(const uint3* __restrict__ recs,
                             const unsigned long long* __restrict__ pos64,
                             const float* __restrict__ llr,
                             float* __restrict__ out,
                             int n2, int n) {
    int i = blockIdx.x * blockDim.x + threadIdx.x;
    if (i >= n2) return;
    ulonglong2 pk2 = *(const ulonglong2*)(pos64 + i * 2);
    float2 ll = *(const float2*)(llr + i * 2);
    int a0 = (int)(pk2.x & 0x1FFFFF);
    int a1 = (int)((pk2.x >> 21) & 0x1FFFFF);
    int a2 = (int)((pk2.x >> 42) & 0x1FFFFF);
    int b0 = (int)(pk2.y & 0x1FFFFF);
    int b1 = (int)((pk2.y >> 21) & 0x1FFFFF);
    int b2 = (int)((pk2.y >> 42) & 0x1FFFFF);
    uint3 ra0 = recs[a0 / DC_C];
    uint3 ra1 = recs[a1 / DC_C];
    uint3 ra2 = recs[a2 / DC_C];
    uint3 rb0 = recs[b0 / DC_C];
    uint3 rb1 = recs[b1 / DC_C];
    uint3 rb2 = recs[b2 / DC_C];
    float pa = ll.x + ((c2v_from_rec(ra0, a0 % DC_C)
                      + c2v_from_rec(ra1, a1 % DC_C))
                      + c2v_from_rec(ra2, a2 % DC_C));
    float pb = ll.y + ((c2v_from_rec(rb0, b0 % DC_C)
                      + c2v_from_rec(rb1, b1 % DC_C))
                      + c2v_from_rec(rb2, b2 % DC_C));
    float2 bits, post;
    bits.x = (pa < 0.0f) ? 1.0f : 0.0f;
    bits.y = (pb < 0.0f) ? 1.0f : 0.0f;
    post.x = pa;
    post.y = pb;
    *(float2*)(out + i * 2) = bits;
    *(float2*)(out + n + i * 2) = post;
}

extern "C" void kernel_launch(void* const* d_in, const int* in_sizes, int n_in,
                              void* d_out, int out_size, void* d_ws, size_t ws_size,
                              hipStream_t stream) {
    const float* llr      = (const float*)d_in[0];
    const float* beta     = (const float*)d_in[1];
    const float* alpha    = (const float*)d_in[2];
    const int*   edge_chk = (const int*)d_in[4];

    const int n  = in_sizes[0];       // 524288
    const int T  = in_sizes[1];       // 10
    const int E  = in_sizes[3];       // 1572864
    const int n_chk = E / DC_C;       // 262144

    // Workspace (rebuilt every call; ws re-poisoned between calls)
    char* ws = (char*)d_ws;
    unsigned int*       cnt8  = (unsigned int*)ws;                    // 128 KB @ 0
    unsigned long long* pos64 = (unsigned long long*)(ws + (1u << 20)); // 4 MB @ 1
    int*                vmap  = (int*)(ws + (5u << 20));              // 6 MB @ 5
    unsigned int*       recs  = (unsigned int*)(ws + (11u << 20));    // 3 MB @ 11
    float*              p     = (float*)(ws + (14u << 20));           // 2 MB @ 14

    hipMemsetAsync(cnt8, 0, (size_t)(n_chk / 8) * 4, stream);
    build_a<<<(n + 255) / 256, 256, 0, stream>>>(edge_chk, cnt8, pos64, n);
    {
        int chunks = (n + VCH - 1) / VCH;
        build_b<<<chunks * NRANGE, 256, 0, stream>>>(pos64, vmap, n, E);
    }
    for (int t = 0; t < T; ++t) {
        const float* src = (t == 0) ? llr : p;   // p_init == llr, c2v_0 == 0
        check_kernel<<<(n_chk + 255) / 256, 256, 0, stream>>>(
            src, vmap, (uint3*)recs, beta, alpha, t, n_chk, (t == 0) ? 1 : 0);
        if (t + 1 < T) {
            var_kernel<<<(n / 2 + 255) / 256, 256, 0, stream>>>(
                (const uint3*)recs, pos64, llr, p, n / 2);
        } else {
            final_kernel<<<(n / 2 + 255) / 256, 256, 0, stream>>>(
                (const uint3*)recs, pos64, llr, (float*)d_out, n / 2, n);
        }
    }
}